// Round 1
// baseline (684.002 us; speedup 1.0000x reference)
//
#include <hip/hip_runtime.h>

// ---------------------------------------------------------------------------
// RoPE GQA attention block, MI355X bf16-MFMA implementation (round 0).
// B=2 S=2048 D=2048 H=16 HKV=4 DH=128.  head h uses kv head h%4 (torch tile).
// Pipeline: cast->bf16, W transposed to [N,K]; QKV GEMMs; RoPE table+apply;
// V transpose; flash attention (16x16x32 MFMA); output GEMM (f32 out).
// ---------------------------------------------------------------------------

typedef __attribute__((ext_vector_type(8))) short  short8;
typedef __attribute__((ext_vector_type(8))) __bf16 bf16x8;
typedef __attribute__((ext_vector_type(4))) float  f32x4;

#define B_   2
#define S_   2048
#define D_   2048
#define H_   16
#define HKV_ 4
#define DH_  128
#define M_   4096  // B*S

static __device__ __forceinline__ ushort f2bf(float f) {
  union { float f; unsigned u; } v; v.f = f;
  unsigned r = (v.u + 0x7fffu + ((v.u >> 16) & 1u)) >> 16;  // RNE
  return (ushort)r;
}
static __device__ __forceinline__ float bf2f(ushort u) {
  union { unsigned u; float f; } v; v.u = ((unsigned)u) << 16;
  return v.f;
}
static __device__ __forceinline__ f32x4 mfma16(short8 a, short8 b, f32x4 c) {
  return __builtin_amdgcn_mfma_f32_16x16x32_bf16(
      __builtin_bit_cast(bf16x8, a), __builtin_bit_cast(bf16x8, b), c, 0, 0, 0);
}

// ---------------- elementwise f32 -> bf16 ----------------------------------
__global__ void conv_f32_bf16(const float* __restrict__ in,
                              ushort* __restrict__ out, int n4) {
  int i = blockIdx.x * blockDim.x + threadIdx.x;
  if (i >= n4) return;
  float4 v = ((const float4*)in)[i];
  ushort4 o;
  o.x = f2bf(v.x); o.y = f2bf(v.y); o.z = f2bf(v.z); o.w = f2bf(v.w);
  ((ushort4*)out)[i] = o;
}

// ---------------- transpose + convert: W[R][C] f32 -> Wt[C][R] bf16 --------
__global__ void transpose_conv(const float* __restrict__ in,
                               ushort* __restrict__ out, int R, int C) {
  __shared__ float tile[32][33];
  int c0 = blockIdx.x * 32, r0 = blockIdx.y * 32;
  int tx = threadIdx.x, ty = threadIdx.y;  // (32,8)
#pragma unroll
  for (int i = 0; i < 32; i += 8)
    tile[ty + i][tx] = in[(size_t)(r0 + ty + i) * C + c0 + tx];
  __syncthreads();
#pragma unroll
  for (int i = 0; i < 32; i += 8)
    out[(size_t)(c0 + ty + i) * R + r0 + tx] = f2bf(tile[tx][ty + i]);
}

// ---------------- bf16 transpose for V: [B,S,kv,128] -> [B,kv,128,S] -------
__global__ void transpose_v(const ushort* __restrict__ in,
                            ushort* __restrict__ out) {
  __shared__ ushort tile[32][33];
  int bkv = blockIdx.z;                       // b*4+kv
  const ushort* src = in + (size_t)(bkv >> 2) * S_ * (HKV_ * DH_) + (bkv & 3) * DH_;
  ushort* dst = out + (size_t)bkv * DH_ * S_;
  int d0 = blockIdx.x * 32, s0 = blockIdx.y * 32;
  int tx = threadIdx.x, ty = threadIdx.y;
#pragma unroll
  for (int i = 0; i < 32; i += 8)
    tile[ty + i][tx] = src[(size_t)(s0 + ty + i) * (HKV_ * DH_) + d0 + tx];
  __syncthreads();
#pragma unroll
  for (int i = 0; i < 32; i += 8)
    dst[(size_t)(d0 + ty + i) * S_ + s0 + tx] = tile[tx][ty + i];
}

// ---------------- RoPE cos/sin table [S][64] -------------------------------
__global__ void rope_table_k(float2* __restrict__ tab) {
  int i = blockIdx.x * blockDim.x + threadIdx.x;  // < S_*64
  int pos = i >> 6, f = i & 63;
  float freq = powf(10000.0f, -(float)f / 64.0f);
  float a = (float)pos * freq;
  tab[i] = make_float2(cosf(a), sinf(a));
}

// ---------------- RoPE in-place on bf16 [rows][cols], pairs (2i,2i+1) ------
__global__ void rope_apply_k(ushort* __restrict__ t,
                             const float2* __restrict__ tab,
                             int total, int ppr_shift) {
  int idx = blockIdx.x * blockDim.x + threadIdx.x;
  if (idx >= total) return;
  int row = idx >> ppr_shift;
  int p   = idx & ((1 << ppr_shift) - 1);
  int head = p >> 6, fi = p & 63;
  int pos = row & (S_ - 1);
  float2 cs = tab[(pos << 6) + fi];
  size_t off = ((size_t)row << (ppr_shift + 1)) + head * DH_ + 2 * fi;
  ushort2 v = *(ushort2*)&t[off];
  float x0 = bf2f(v.x), x1 = bf2f(v.y);
  ushort2 o;
  o.x = f2bf(x0 * cs.x - x1 * cs.y);
  o.y = f2bf(x0 * cs.y + x1 * cs.x);
  *(ushort2*)&t[off] = o;
}

// ---------------- bf16 GEMM: C[M,N] = A[M,K] * Bt[N,K]^T -------------------
// 128x128 tile, BK=32, 4 waves (2x2), each wave 64x64 = 4x4 16x16 frags.
template <typename OutT>
__global__ __launch_bounds__(256) void gemm_bt(const ushort* __restrict__ A,
                                               const ushort* __restrict__ Bt,
                                               OutT* __restrict__ C,
                                               int M, int N, int K) {
  __shared__ ushort As[128 * 32];
  __shared__ ushort Bs[128 * 32];
  const int tid = threadIdx.x;
  const int lane = tid & 63, wave = tid >> 6;
  const int wm = (wave >> 1) * 64, wn = (wave & 1) * 64;
  const int bm = blockIdx.x * 128, bn = blockIdx.y * 128;
  const int l16 = lane & 15, l4 = lane >> 4;

  const int r0 = tid >> 2;         // 0..63: staged row within half-tile
  const int kc = (tid & 3) * 8;    // k offset 0,8,16,24
  const ushort* ga0 = A  + (size_t)(bm + r0) * K + kc;
  const ushort* ga1 = A  + (size_t)(bm + 64 + r0) * K + kc;
  const ushort* gb0 = Bt + (size_t)(bn + r0) * K + kc;
  const ushort* gb1 = Bt + (size_t)(bn + 64 + r0) * K + kc;

  f32x4 acc[4][4] = {};

  for (int k0 = 0; k0 < K; k0 += 32) {
    short8 av0 = *(const short8*)(ga0 + k0);
    short8 av1 = *(const short8*)(ga1 + k0);
    short8 bv0 = *(const short8*)(gb0 + k0);
    short8 bv1 = *(const short8*)(gb1 + k0);
    __syncthreads();                       // readers of prev tile done
    *(short8*)&As[(r0)      * 32 + kc] = av0;
    *(short8*)&As[(64 + r0) * 32 + kc] = av1;
    *(short8*)&Bs[(r0)      * 32 + kc] = bv0;
    *(short8*)&Bs[(64 + r0) * 32 + kc] = bv1;
    __syncthreads();                       // tile visible
    short8 af[4], bf[4];
#pragma unroll
    for (int m = 0; m < 4; ++m)
      af[m] = *(const short8*)&As[(wm + m * 16 + l16) * 32 + l4 * 8];
#pragma unroll
    for (int n = 0; n < 4; ++n)
      bf[n] = *(const short8*)&Bs[(wn + n * 16 + l16) * 32 + l4 * 8];
#pragma unroll
    for (int m = 0; m < 4; ++m)
#pragma unroll
      for (int n = 0; n < 4; ++n)
        acc[m][n] = mfma16(af[m], bf[n], acc[m][n]);
  }

  // epilogue: C/D layout col=lane&15, row=(lane>>4)*4+reg
#pragma unroll
  for (int m = 0; m < 4; ++m) {
#pragma unroll
    for (int n = 0; n < 4; ++n) {
#pragma unroll
      for (int r = 0; r < 4; ++r) {
        size_t row = bm + wm + m * 16 + l4 * 4 + r;
        size_t col = bn + wn + n * 16 + l16;
        if constexpr (sizeof(OutT) == 2)
          C[row * N + col] = f2bf(acc[m][n][r]);
        else
          C[row * N + col] = acc[m][n][r];
      }
    }
  }
}

// ---------------- flash attention ------------------------------------------
// grid (S/64, B*H); 4 waves/block, wave owns 16 q rows; KBLK=32 keys/iter.
__global__ __launch_bounds__(256) void flash_attn(const ushort* __restrict__ Q,
                                                  const ushort* __restrict__ K,
                                                  const ushort* __restrict__ Vt,
                                                  ushort* __restrict__ Oa) {
  __shared__ ushort P_lds[4][16 * 32];  // per-wave P tile
  const int tid = threadIdx.x;
  const int lane = tid & 63, wave = tid >> 6;
  const int l16 = lane & 15, l4 = lane >> 4;
  const int bh = blockIdx.y;
  const int b = bh >> 4, h = bh & 15, kv = h & 3;
  const int q0 = blockIdx.x * 64 + wave * 16;

  // Q fragments: A[row=q=l16][k=d=(l4*8..)+kk*32], held for whole kernel
  short8 qf[4];
  const ushort* qrow = Q + ((size_t)(b * S_ + q0 + l16)) * D_ + h * DH_ + l4 * 8;
#pragma unroll
  for (int kk = 0; kk < 4; ++kk) qf[kk] = *(const short8*)(qrow + kk * 32);

  // K: B[k=d][col=key]; per-lane base at key=l16, d=l4*8
  const ushort* kptr = K + ((size_t)(b * S_) + l16) * (HKV_ * DH_) + kv * DH_ + l4 * 8;
  // Vt: B[k=key][col=d]; per-lane base at d=l16, key=l4*8
  const ushort* vptr = Vt + ((size_t)(b * HKV_ + kv) * DH_ + l16) * S_ + l4 * 8;

  float m[4], l[4];
  f32x4 o[8] = {};
#pragma unroll
  for (int r = 0; r < 4; ++r) { m[r] = -1e30f; l[r] = 0.f; }
  const float sc = 0.08838834764831845f;  // 1/sqrt(128)

  for (int t = 0; t < S_ / 32; ++t) {
    f32x4 s0 = {0.f, 0.f, 0.f, 0.f}, s1 = {0.f, 0.f, 0.f, 0.f};
#pragma unroll
    for (int kk = 0; kk < 4; ++kk) {
      short8 kf0 = *(const short8*)(kptr + (size_t)(t * 32)      * (HKV_ * DH_) + kk * 32);
      short8 kf1 = *(const short8*)(kptr + (size_t)(t * 32 + 16) * (HKV_ * DH_) + kk * 32);
      s0 = mfma16(qf[kk], kf0, s0);
      s1 = mfma16(qf[kk], kf1, s1);
    }
    // online softmax per q-row r (row = l4*4+r, key col = c*16+l16)
    float alpha[4];
#pragma unroll
    for (int r = 0; r < 4; ++r) {
      float v0 = s0[r] * sc, v1 = s1[r] * sc;
      float mx = fmaxf(v0, v1);
#pragma unroll
      for (int off = 1; off < 16; off <<= 1) mx = fmaxf(mx, __shfl_xor(mx, off));
      float mn = fmaxf(m[r], mx);
      alpha[r] = __expf(m[r] - mn);
      m[r] = mn;
      float p0 = __expf(v0 - mn), p1 = __expf(v1 - mn);
      float ps = p0 + p1;
#pragma unroll
      for (int off = 1; off < 16; off <<= 1) ps += __shfl_xor(ps, off);
      l[r] = l[r] * alpha[r] + ps;
      ushort* pl = &P_lds[wave][(l4 * 4 + r) * 32 + l16];
      pl[0]  = f2bf(p0);
      pl[16] = f2bf(p1);
    }
    // rescale accumulators
#pragma unroll
    for (int g = 0; g < 8; ++g)
#pragma unroll
      for (int r = 0; r < 4; ++r) o[g][r] *= alpha[r];
    // PV: A[row=q=l16][k=key=l4*8+j] from P_lds; B[k=key][col=d] from Vt
    short8 pa = *(const short8*)&P_lds[wave][l16 * 32 + l4 * 8];
#pragma unroll
    for (int g = 0; g < 8; ++g) {
      short8 vf = *(const short8*)(vptr + (size_t)g * 16 * S_ + t * 32);
      o[g] = mfma16(pa, vf, o[g]);
    }
  }

  float inv[4];
#pragma unroll
  for (int r = 0; r < 4; ++r) inv[r] = 1.0f / l[r];
  ushort* op = Oa + (size_t)(b * S_ + q0) * D_ + h * DH_;
#pragma unroll
  for (int g = 0; g < 8; ++g)
#pragma unroll
    for (int r = 0; r < 4; ++r)
      op[(size_t)(l4 * 4 + r) * D_ + g * 16 + l16] = f2bf(o[g][r] * inv[r]);
}

// ---------------------------------------------------------------------------
extern "C" void kernel_launch(void* const* d_in, const int* in_sizes, int n_in,
                              void* d_out, int out_size, void* d_ws, size_t ws_size,
                              hipStream_t stream) {
  (void)in_sizes; (void)n_in; (void)out_size; (void)ws_size;
  const float* x  = (const float*)d_in[0];
  const float* Wq = (const float*)d_in[1];
  const float* Wk = (const float*)d_in[2];
  const float* Wv = (const float*)d_in[3];
  const float* Wo = (const float*)d_in[4];
  float* out = (float*)d_out;

  size_t off = 0;
  auto carve = [&](size_t bytes) -> void* {
    void* p = (char*)d_ws + off;
    off += (bytes + 255) & ~(size_t)255;
    return p;
  };
  ushort* xb   = (ushort*)carve((size_t)M_ * D_ * 2);
  ushort* Wqt  = (ushort*)carve((size_t)D_ * D_ * 2);
  ushort* Wkt  = (ushort*)carve((size_t)512 * D_ * 2);
  ushort* Wvt  = (ushort*)carve((size_t)512 * D_ * 2);
  ushort* Wot  = (ushort*)carve((size_t)D_ * D_ * 2);
  ushort* Qb   = (ushort*)carve((size_t)M_ * D_ * 2);
  ushort* Kb   = (ushort*)carve((size_t)M_ * 512 * 2);
  ushort* Vb   = (ushort*)carve((size_t)M_ * 512 * 2);
  ushort* Vt   = (ushort*)carve((size_t)M_ * 512 * 2);
  ushort* attn = (ushort*)carve((size_t)M_ * D_ * 2);
  float2* tab  = (float2*)carve((size_t)S_ * 64 * sizeof(float2));

  // 1. casts / transposes of inputs
  conv_f32_bf16<<<(M_ * D_ / 4 + 255) / 256, 256, 0, stream>>>(x, xb, M_ * D_ / 4);
  transpose_conv<<<dim3(64, 64), dim3(32, 8), 0, stream>>>(Wq, Wqt, 2048, 2048);
  transpose_conv<<<dim3(16, 64), dim3(32, 8), 0, stream>>>(Wk, Wkt, 2048, 512);
  transpose_conv<<<dim3(16, 64), dim3(32, 8), 0, stream>>>(Wv, Wvt, 2048, 512);
  transpose_conv<<<dim3(64, 64), dim3(32, 8), 0, stream>>>(Wo, Wot, 2048, 2048);
  rope_table_k<<<(S_ * 64) / 256, 256, 0, stream>>>(tab);

  // 2. projections
  gemm_bt<ushort><<<dim3(32, 16), 256, 0, stream>>>(xb, Wqt, Qb, M_, 2048, 2048);
  gemm_bt<ushort><<<dim3(32, 4),  256, 0, stream>>>(xb, Wkt, Kb, M_, 512, 2048);
  gemm_bt<ushort><<<dim3(32, 4),  256, 0, stream>>>(xb, Wvt, Vb, M_, 512, 2048);

  // 3. RoPE (in place), V transpose
  rope_apply_k<<<(M_ * 1024) / 256, 256, 0, stream>>>(Qb, tab, M_ * 1024, 10);
  rope_apply_k<<<(M_ * 256) / 256, 256, 0, stream>>>(Kb, tab, M_ * 256, 8);
  transpose_v<<<dim3(4, 64, 8), dim3(32, 8), 0, stream>>>(Vb, Vt);

  // 4. attention
  flash_attn<<<dim3(S_ / 64, B_ * H_), 256, 0, stream>>>(Qb, Kb, Vt, attn);

  // 5. output projection (f32 out)
  gemm_bt<float><<<dim3(32, 16), 256, 0, stream>>>(attn, Wot, out, M_, 2048, 2048);
}

// Round 2
// 400.538 us; speedup vs baseline: 1.7077x; 1.7077x over previous
//
#include <hip/hip_runtime.h>

// ---------------------------------------------------------------------------
// RoPE GQA attention block, MI355X bf16-MFMA implementation (round 2).
// B=2 S=2048 D=2048 H=16 HKV=4 DH=128.  head h uses kv head h%4 (torch tile).
// Round 2: flash_attn rebuilt — LDS-staged K/V tiles (coalesced), XOR-swizzled
// LDS (T2), register-prefetch of next tile (T14), KBLK=64.
// ---------------------------------------------------------------------------

typedef __attribute__((ext_vector_type(8))) short  short8;
typedef __attribute__((ext_vector_type(8))) __bf16 bf16x8;
typedef __attribute__((ext_vector_type(4))) float  f32x4;

#define B_   2
#define S_   2048
#define D_   2048
#define H_   16
#define HKV_ 4
#define DH_  128
#define M_   4096  // B*S

static __device__ __forceinline__ ushort f2bf(float f) {
  union { float f; unsigned u; } v; v.f = f;
  unsigned r = (v.u + 0x7fffu + ((v.u >> 16) & 1u)) >> 16;  // RNE
  return (ushort)r;
}
static __device__ __forceinline__ float bf2f(ushort u) {
  union { unsigned u; float f; } v; v.u = ((unsigned)u) << 16;
  return v.f;
}
static __device__ __forceinline__ f32x4 mfma16(short8 a, short8 b, f32x4 c) {
  return __builtin_amdgcn_mfma_f32_16x16x32_bf16(
      __builtin_bit_cast(bf16x8, a), __builtin_bit_cast(bf16x8, b), c, 0, 0, 0);
}

// ---------------- elementwise f32 -> bf16 ----------------------------------
__global__ void conv_f32_bf16(const float* __restrict__ in,
                              ushort* __restrict__ out, int n4) {
  int i = blockIdx.x * blockDim.x + threadIdx.x;
  if (i >= n4) return;
  float4 v = ((const float4*)in)[i];
  ushort4 o;
  o.x = f2bf(v.x); o.y = f2bf(v.y); o.z = f2bf(v.z); o.w = f2bf(v.w);
  ((ushort4*)out)[i] = o;
}

// ---------------- transpose + convert: W[R][C] f32 -> Wt[C][R] bf16 --------
__global__ void transpose_conv(const float* __restrict__ in,
                               ushort* __restrict__ out, int R, int C) {
  __shared__ float tile[32][33];
  int c0 = blockIdx.x * 32, r0 = blockIdx.y * 32;
  int tx = threadIdx.x, ty = threadIdx.y;  // (32,8)
#pragma unroll
  for (int i = 0; i < 32; i += 8)
    tile[ty + i][tx] = in[(size_t)(r0 + ty + i) * C + c0 + tx];
  __syncthreads();
#pragma unroll
  for (int i = 0; i < 32; i += 8)
    out[(size_t)(c0 + ty + i) * R + r0 + tx] = f2bf(tile[tx][ty + i]);
}

// ---------------- bf16 transpose for V: [B,S,kv,128] -> [B,kv,128,S] -------
__global__ void transpose_v(const ushort* __restrict__ in,
                            ushort* __restrict__ out) {
  __shared__ ushort tile[32][33];
  int bkv = blockIdx.z;                       // b*4+kv
  const ushort* src = in + (size_t)(bkv >> 2) * S_ * (HKV_ * DH_) + (bkv & 3) * DH_;
  ushort* dst = out + (size_t)bkv * DH_ * S_;
  int d0 = blockIdx.x * 32, s0 = blockIdx.y * 32;
  int tx = threadIdx.x, ty = threadIdx.y;
#pragma unroll
  for (int i = 0; i < 32; i += 8)
    tile[ty + i][tx] = src[(size_t)(s0 + ty + i) * (HKV_ * DH_) + d0 + tx];
  __syncthreads();
#pragma unroll
  for (int i = 0; i < 32; i += 8)
    dst[(size_t)(d0 + ty + i) * S_ + s0 + tx] = tile[tx][ty + i];
}

// ---------------- RoPE cos/sin table [S][64] -------------------------------
__global__ void rope_table_k(float2* __restrict__ tab) {
  int i = blockIdx.x * blockDim.x + threadIdx.x;  // < S_*64
  int pos = i >> 6, f = i & 63;
  float freq = powf(10000.0f, -(float)f / 64.0f);
  float a = (float)pos * freq;
  tab[i] = make_float2(cosf(a), sinf(a));
}

// ---------------- RoPE in-place on bf16 [rows][cols], pairs (2i,2i+1) ------
__global__ void rope_apply_k(ushort* __restrict__ t,
                             const float2* __restrict__ tab,
                             int total, int ppr_shift) {
  int idx = blockIdx.x * blockDim.x + threadIdx.x;
  if (idx >= total) return;
  int row = idx >> ppr_shift;
  int p   = idx & ((1 << ppr_shift) - 1);
  int head = p >> 6, fi = p & 63;
  int pos = row & (S_ - 1);
  float2 cs = tab[(pos << 6) + fi];
  size_t off = ((size_t)row << (ppr_shift + 1)) + head * DH_ + 2 * fi;
  ushort2 v = *(ushort2*)&t[off];
  float x0 = bf2f(v.x), x1 = bf2f(v.y);
  ushort2 o;
  o.x = f2bf(x0 * cs.x - x1 * cs.y);
  o.y = f2bf(x0 * cs.y + x1 * cs.x);
  *(ushort2*)&t[off] = o;
}

// ---------------- bf16 GEMM: C[M,N] = A[M,K] * Bt[N,K]^T -------------------
// 128x128 tile, BK=32, 4 waves (2x2), each wave 64x64 = 4x4 16x16 frags.
template <typename OutT>
__global__ __launch_bounds__(256) void gemm_bt(const ushort* __restrict__ A,
                                               const ushort* __restrict__ Bt,
                                               OutT* __restrict__ C,
                                               int M, int N, int K) {
  __shared__ ushort As[128 * 32];
  __shared__ ushort Bs[128 * 32];
  const int tid = threadIdx.x;
  const int lane = tid & 63, wave = tid >> 6;
  const int wm = (wave >> 1) * 64, wn = (wave & 1) * 64;
  const int bm = blockIdx.x * 128, bn = blockIdx.y * 128;
  const int l16 = lane & 15, l4 = lane >> 4;

  const int r0 = tid >> 2;         // 0..63: staged row within half-tile
  const int kc = (tid & 3) * 8;    // k offset 0,8,16,24
  const ushort* ga0 = A  + (size_t)(bm + r0) * K + kc;
  const ushort* ga1 = A  + (size_t)(bm + 64 + r0) * K + kc;
  const ushort* gb0 = Bt + (size_t)(bn + r0) * K + kc;
  const ushort* gb1 = Bt + (size_t)(bn + 64 + r0) * K + kc;

  f32x4 acc[4][4] = {};

  for (int k0 = 0; k0 < K; k0 += 32) {
    short8 av0 = *(const short8*)(ga0 + k0);
    short8 av1 = *(const short8*)(ga1 + k0);
    short8 bv0 = *(const short8*)(gb0 + k0);
    short8 bv1 = *(const short8*)(gb1 + k0);
    __syncthreads();                       // readers of prev tile done
    *(short8*)&As[(r0)      * 32 + kc] = av0;
    *(short8*)&As[(64 + r0) * 32 + kc] = av1;
    *(short8*)&Bs[(r0)      * 32 + kc] = bv0;
    *(short8*)&Bs[(64 + r0) * 32 + kc] = bv1;
    __syncthreads();                       // tile visible
    short8 af[4], bfr[4];
#pragma unroll
    for (int m = 0; m < 4; ++m)
      af[m] = *(const short8*)&As[(wm + m * 16 + l16) * 32 + l4 * 8];
#pragma unroll
    for (int n = 0; n < 4; ++n)
      bfr[n] = *(const short8*)&Bs[(wn + n * 16 + l16) * 32 + l4 * 8];
#pragma unroll
    for (int m = 0; m < 4; ++m)
#pragma unroll
      for (int n = 0; n < 4; ++n)
        acc[m][n] = mfma16(af[m], bfr[n], acc[m][n]);
  }

  // epilogue: C/D layout col=lane&15, row=(lane>>4)*4+reg
#pragma unroll
  for (int m = 0; m < 4; ++m) {
#pragma unroll
    for (int n = 0; n < 4; ++n) {
#pragma unroll
      for (int r = 0; r < 4; ++r) {
        size_t row = bm + wm + m * 16 + l4 * 4 + r;
        size_t col = bn + wn + n * 16 + l16;
        if constexpr (sizeof(OutT) == 2)
          C[row * N + col] = f2bf(acc[m][n][r]);
        else
          C[row * N + col] = acc[m][n][r];
      }
    }
  }
}

// ---------------- flash attention (round 2) --------------------------------
// grid (S/64, B*H); 4 waves/block, wave owns 16 q rows; KBLK=64 keys/iter.
// K/V tiles staged in swizzled LDS (T2); next tile prefetched to regs (T14).
__global__ __launch_bounds__(256) void flash_attn(const ushort* __restrict__ Q,
                                                  const ushort* __restrict__ K,
                                                  const ushort* __restrict__ Vt,
                                                  ushort* __restrict__ Oa) {
  __shared__ ushort Ks[64 * 128];       // [key][d], swizzled
  __shared__ ushort Vs[128 * 64];       // [d][key], swizzled
  __shared__ ushort Ps[4][16 * 64];     // per-wave P [q][key], swizzled
  const int tid = threadIdx.x;
  const int lane = tid & 63, wave = tid >> 6;
  const int l16 = lane & 15, l4 = lane >> 4;
  const int bh = blockIdx.y;
  const int b = bh >> 4, h = bh & 15, kv = h & 3;
  const int q0 = blockIdx.x * 64 + wave * 16;

  // Q fragments: A[row=q=l16][k=d], held in regs for whole kernel
  short8 qf[4];
  const ushort* qrow = Q + ((size_t)(b * S_ + q0 + l16)) * D_ + h * DH_ + l4 * 8;
#pragma unroll
  for (int kk = 0; kk < 4; ++kk) qf[kk] = *(const short8*)(qrow + kk * 32);

  // cooperative staging: K rows are 256B (16 thr/row), V rows 128B (8 thr/row)
  const int krow = tid >> 4, kcol = (tid & 15) * 8;
  const int vrow = tid >> 3, vcol = (tid & 7) * 8;
  const ushort* kbase = K  + ((size_t)b * S_ + krow) * (HKV_ * DH_) + kv * DH_ + kcol;
  const ushort* vbase = Vt + ((size_t)(b * HKV_ + kv) * DH_ + vrow) * S_ + vcol;
  int kw[4], vw[4];
#pragma unroll
  for (int p = 0; p < 4; ++p) {
    int r = krow + p * 16;
    kw[p] = r * 128 + (kcol ^ ((r & 7) << 3));
    int d = vrow + p * 32;
    vw[p] = d * 64 + (vcol ^ ((d & 7) << 3));
  }

  float mreg[4], lreg[4];
  f32x4 o[8] = {};
#pragma unroll
  for (int r = 0; r < 4; ++r) { mreg[r] = -1e30f; lreg[r] = 0.f; }
  const float sc = 0.08838834764831845f;  // 1/sqrt(128)

  const int NT = S_ / 64;
  short8 kr[4], vr[4];
  auto loadt = [&](int t) {
#pragma unroll
    for (int p = 0; p < 4; ++p) {
      kr[p] = *(const short8*)(kbase + ((size_t)t * 64 + p * 16) * (HKV_ * DH_));
      vr[p] = *(const short8*)(vbase + (size_t)p * 32 * S_ + t * 64);
    }
  };

  loadt(0);
  for (int t = 0; t < NT; ++t) {
    __syncthreads();                      // all waves done reading prev tile
#pragma unroll
    for (int p = 0; p < 4; ++p) {
      *(short8*)&Ks[kw[p]] = kr[p];
      *(short8*)&Vs[vw[p]] = vr[p];
    }
    __syncthreads();                      // tile visible
    if (t + 1 < NT) loadt(t + 1);         // prefetch overlaps compute (T14)

    // QK^T: s[c] covers keys c*16..c*16+15
    f32x4 s[4] = {};
#pragma unroll
    for (int c = 0; c < 4; ++c) {
      const int key = c * 16 + l16;
      const int swz = (key & 7) << 3;
#pragma unroll
      for (int kk = 0; kk < 4; ++kk) {
        short8 kf = *(const short8*)&Ks[key * 128 + ((kk * 32 + l4 * 8) ^ swz)];
        s[c] = mfma16(qf[kk], kf, s[c]);
      }
    }

    // online softmax per q-row r (row = l4*4+r), 64 keys
    float alpha[4];
#pragma unroll
    for (int r = 0; r < 4; ++r) {
      float v0 = s[0][r] * sc, v1 = s[1][r] * sc;
      float v2 = s[2][r] * sc, v3 = s[3][r] * sc;
      float mx = fmaxf(fmaxf(v0, v1), fmaxf(v2, v3));
#pragma unroll
      for (int off = 1; off < 16; off <<= 1) mx = fmaxf(mx, __shfl_xor(mx, off));
      float mn = fmaxf(mreg[r], mx);
      alpha[r] = __expf(mreg[r] - mn);
      mreg[r] = mn;
      float p0 = __expf(v0 - mn), p1 = __expf(v1 - mn);
      float p2 = __expf(v2 - mn), p3 = __expf(v3 - mn);
      float ps = p0 + p1 + p2 + p3;
#pragma unroll
      for (int off = 1; off < 16; off <<= 1) ps += __shfl_xor(ps, off);
      lreg[r] = lreg[r] * alpha[r] + ps;
      const int prow = l4 * 4 + r;
      const int pswz = (prow & 7) << 3;
      ushort* pl = &Ps[wave][prow * 64];
      pl[(l16)      ^ pswz] = f2bf(p0);
      pl[(16 + l16) ^ pswz] = f2bf(p1);
      pl[(32 + l16) ^ pswz] = f2bf(p2);
      pl[(48 + l16) ^ pswz] = f2bf(p3);
    }

    // rescale accumulators
#pragma unroll
    for (int g = 0; g < 8; ++g)
#pragma unroll
      for (int r = 0; r < 4; ++r) o[g][r] *= alpha[r];

    // PV: A = P[16q][64k] from Ps; B = V^T[k][d] from Vs
    const int pswzA = (l16 & 7) << 3;
#pragma unroll
    for (int ks = 0; ks < 2; ++ks) {
      short8 pa = *(const short8*)&Ps[wave][l16 * 64 + ((ks * 32 + l4 * 8) ^ pswzA)];
#pragma unroll
      for (int g = 0; g < 8; ++g) {
        const int d = g * 16 + l16;
        short8 vf = *(const short8*)&Vs[d * 64 + ((ks * 32 + l4 * 8) ^ ((d & 7) << 3))];
        o[g] = mfma16(pa, vf, o[g]);
      }
    }
  }

  float inv[4];
#pragma unroll
  for (int r = 0; r < 4; ++r) inv[r] = 1.0f / lreg[r];
  ushort* op = Oa + (size_t)(b * S_ + q0) * D_ + h * DH_;
#pragma unroll
  for (int g = 0; g < 8; ++g)
#pragma unroll
    for (int r = 0; r < 4; ++r)
      op[(size_t)(l4 * 4 + r) * D_ + g * 16 + l16] = f2bf(o[g][r] * inv[r]);
}

// ---------------------------------------------------------------------------
extern "C" void kernel_launch(void* const* d_in, const int* in_sizes, int n_in,
                              void* d_out, int out_size, void* d_ws, size_t ws_size,
                              hipStream_t stream) {
  (void)in_sizes; (void)n_in; (void)out_size; (void)ws_size;
  const float* x  = (const float*)d_in[0];
  const float* Wq = (const float*)d_in[1];
  const float* Wk = (const float*)d_in[2];
  const float* Wv = (const float*)d_in[3];
  const float* Wo = (const float*)d_in[4];
  float* out = (float*)d_out;

  size_t off = 0;
  auto carve = [&](size_t bytes) -> void* {
    void* p = (char*)d_ws + off;
    off += (bytes + 255) & ~(size_t)255;
    return p;
  };
  ushort* xb   = (ushort*)carve((size_t)M_ * D_ * 2);
  ushort* Wqt  = (ushort*)carve((size_t)D_ * D_ * 2);
  ushort* Wkt  = (ushort*)carve((size_t)512 * D_ * 2);
  ushort* Wvt  = (ushort*)carve((size_t)512 * D_ * 2);
  ushort* Wot  = (ushort*)carve((size_t)D_ * D_ * 2);
  ushort* Qb   = (ushort*)carve((size_t)M_ * D_ * 2);
  ushort* Kb   = (ushort*)carve((size_t)M_ * 512 * 2);
  ushort* Vb   = (ushort*)carve((size_t)M_ * 512 * 2);
  ushort* Vt   = (ushort*)carve((size_t)M_ * 512 * 2);
  ushort* attn = (ushort*)carve((size_t)M_ * D_ * 2);
  float2* tab  = (float2*)carve((size_t)S_ * 64 * sizeof(float2));

  // 1. casts / transposes of inputs
  conv_f32_bf16<<<(M_ * D_ / 4 + 255) / 256, 256, 0, stream>>>(x, xb, M_ * D_ / 4);
  transpose_conv<<<dim3(64, 64), dim3(32, 8), 0, stream>>>(Wq, Wqt, 2048, 2048);
  transpose_conv<<<dim3(16, 64), dim3(32, 8), 0, stream>>>(Wk, Wkt, 2048, 512);
  transpose_conv<<<dim3(16, 64), dim3(32, 8), 0, stream>>>(Wv, Wvt, 2048, 512);
  transpose_conv<<<dim3(64, 64), dim3(32, 8), 0, stream>>>(Wo, Wot, 2048, 2048);
  rope_table_k<<<(S_ * 64) / 256, 256, 0, stream>>>(tab);

  // 2. projections
  gemm_bt<ushort><<<dim3(32, 16), 256, 0, stream>>>(xb, Wqt, Qb, M_, 2048, 2048);
  gemm_bt<ushort><<<dim3(32, 4),  256, 0, stream>>>(xb, Wkt, Kb, M_, 512, 2048);
  gemm_bt<ushort><<<dim3(32, 4),  256, 0, stream>>>(xb, Wvt, Vb, M_, 512, 2048);

  // 3. RoPE (in place), V transpose
  rope_apply_k<<<(M_ * 1024) / 256, 256, 0, stream>>>(Qb, tab, M_ * 1024, 10);
  rope_apply_k<<<(M_ * 256) / 256, 256, 0, stream>>>(Kb, tab, M_ * 256, 8);
  transpose_v<<<dim3(4, 64, 8), dim3(32, 8), 0, stream>>>(Vb, Vt);

  // 4. attention
  flash_attn<<<dim3(S_ / 64, B_ * H_), 256, 0, stream>>>(Qb, Kb, Vt, attn);

  // 5. output projection (f32 out)
  gemm_bt<float><<<dim3(32, 16), 256, 0, stream>>>(attn, Wot, out, M_, 2048, 2048);
}

// Round 3
// 346.124 us; speedup vs baseline: 1.9762x; 1.1572x over previous
//
#include <hip/hip_runtime.h>

// ---------------------------------------------------------------------------
// RoPE GQA attention block, MI355X bf16-MFMA implementation (round 3).
// B=2 S=2048 D=2048 H=16 HKV=4 DH=128.  head h uses kv head h%4 (torch tile).
// Round 3: swapped QK^T (mfma(K,Q)) -> lane owns a full q-row slice; softmax
// in-register (2 shuffles vs 40), packed ushort4 P-stores, defer-max (T13),
// exp2 with scale pre-folded into Q during RoPE.
// ---------------------------------------------------------------------------

typedef __attribute__((ext_vector_type(8))) short  short8;
typedef __attribute__((ext_vector_type(8))) __bf16 bf16x8;
typedef __attribute__((ext_vector_type(4))) float  f32x4;

#define B_   2
#define S_   2048
#define D_   2048
#define H_   16
#define HKV_ 4
#define DH_  128
#define M_   4096  // B*S

static __device__ __forceinline__ ushort f2bf(float f) {
  union { float f; unsigned u; } v; v.f = f;
  unsigned r = (v.u + 0x7fffu + ((v.u >> 16) & 1u)) >> 16;  // RNE
  return (ushort)r;
}
static __device__ __forceinline__ float bf2f(ushort u) {
  union { unsigned u; float f; } v; v.u = ((unsigned)u) << 16;
  return v.f;
}
static __device__ __forceinline__ f32x4 mfma16(short8 a, short8 b, f32x4 c) {
  return __builtin_amdgcn_mfma_f32_16x16x32_bf16(
      __builtin_bit_cast(bf16x8, a), __builtin_bit_cast(bf16x8, b), c, 0, 0, 0);
}

// ---------------- elementwise f32 -> bf16 ----------------------------------
__global__ void conv_f32_bf16(const float* __restrict__ in,
                              ushort* __restrict__ out, int n4) {
  int i = blockIdx.x * blockDim.x + threadIdx.x;
  if (i >= n4) return;
  float4 v = ((const float4*)in)[i];
  ushort4 o;
  o.x = f2bf(v.x); o.y = f2bf(v.y); o.z = f2bf(v.z); o.w = f2bf(v.w);
  ((ushort4*)out)[i] = o;
}

// ---------------- transpose + convert: W[R][C] f32 -> Wt[C][R] bf16 --------
__global__ void transpose_conv(const float* __restrict__ in,
                               ushort* __restrict__ out, int R, int C) {
  __shared__ float tile[32][33];
  int c0 = blockIdx.x * 32, r0 = blockIdx.y * 32;
  int tx = threadIdx.x, ty = threadIdx.y;  // (32,8)
#pragma unroll
  for (int i = 0; i < 32; i += 8)
    tile[ty + i][tx] = in[(size_t)(r0 + ty + i) * C + c0 + tx];
  __syncthreads();
#pragma unroll
  for (int i = 0; i < 32; i += 8)
    out[(size_t)(c0 + ty + i) * R + r0 + tx] = f2bf(tile[tx][ty + i]);
}

// ---------------- bf16 transpose for V: [B,S,kv,128] -> [B,kv,128,S] -------
__global__ void transpose_v(const ushort* __restrict__ in,
                            ushort* __restrict__ out) {
  __shared__ ushort tile[32][33];
  int bkv = blockIdx.z;                       // b*4+kv
  const ushort* src = in + (size_t)(bkv >> 2) * S_ * (HKV_ * DH_) + (bkv & 3) * DH_;
  ushort* dst = out + (size_t)bkv * DH_ * S_;
  int d0 = blockIdx.x * 32, s0 = blockIdx.y * 32;
  int tx = threadIdx.x, ty = threadIdx.y;
#pragma unroll
  for (int i = 0; i < 32; i += 8)
    tile[ty + i][tx] = src[(size_t)(s0 + ty + i) * (HKV_ * DH_) + d0 + tx];
  __syncthreads();
#pragma unroll
  for (int i = 0; i < 32; i += 8)
    dst[(size_t)(d0 + ty + i) * S_ + s0 + tx] = tile[tx][ty + i];
}

// ---------------- RoPE cos/sin table [S][64] -------------------------------
__global__ void rope_table_k(float2* __restrict__ tab) {
  int i = blockIdx.x * blockDim.x + threadIdx.x;  // < S_*64
  int pos = i >> 6, f = i & 63;
  float freq = powf(10000.0f, -(float)f / 64.0f);
  float a = (float)pos * freq;
  tab[i] = make_float2(cosf(a), sinf(a));
}

// ---------------- RoPE in-place on bf16 [rows][cols], pairs (2i,2i+1) ------
// oscale is folded into the rotated output (used to pre-scale Q by
// 1/sqrt(Dh) * log2(e) so attention can use exp2 directly).
__global__ void rope_apply_k(ushort* __restrict__ t,
                             const float2* __restrict__ tab,
                             int total, int ppr_shift, float oscale) {
  int idx = blockIdx.x * blockDim.x + threadIdx.x;
  if (idx >= total) return;
  int row = idx >> ppr_shift;
  int p   = idx & ((1 << ppr_shift) - 1);
  int head = p >> 6, fi = p & 63;
  int pos = row & (S_ - 1);
  float2 cs = tab[(pos << 6) + fi];
  size_t off = ((size_t)row << (ppr_shift + 1)) + head * DH_ + 2 * fi;
  ushort2 v = *(ushort2*)&t[off];
  float x0 = bf2f(v.x), x1 = bf2f(v.y);
  ushort2 o;
  o.x = f2bf((x0 * cs.x - x1 * cs.y) * oscale);
  o.y = f2bf((x0 * cs.y + x1 * cs.x) * oscale);
  *(ushort2*)&t[off] = o;
}

// ---------------- bf16 GEMM: C[M,N] = A[M,K] * Bt[N,K]^T -------------------
// 128x128 tile, BK=32, 4 waves (2x2), each wave 64x64 = 4x4 16x16 frags.
template <typename OutT>
__global__ __launch_bounds__(256) void gemm_bt(const ushort* __restrict__ A,
                                               const ushort* __restrict__ Bt,
                                               OutT* __restrict__ C,
                                               int M, int N, int K) {
  __shared__ ushort As[128 * 32];
  __shared__ ushort Bs[128 * 32];
  const int tid = threadIdx.x;
  const int lane = tid & 63, wave = tid >> 6;
  const int wm = (wave >> 1) * 64, wn = (wave & 1) * 64;
  const int bm = blockIdx.x * 128, bn = blockIdx.y * 128;
  const int l16 = lane & 15, l4 = lane >> 4;

  const int r0 = tid >> 2;         // 0..63: staged row within half-tile
  const int kc = (tid & 3) * 8;    // k offset 0,8,16,24
  const ushort* ga0 = A  + (size_t)(bm + r0) * K + kc;
  const ushort* ga1 = A  + (size_t)(bm + 64 + r0) * K + kc;
  const ushort* gb0 = Bt + (size_t)(bn + r0) * K + kc;
  const ushort* gb1 = Bt + (size_t)(bn + 64 + r0) * K + kc;

  f32x4 acc[4][4] = {};

  for (int k0 = 0; k0 < K; k0 += 32) {
    short8 av0 = *(const short8*)(ga0 + k0);
    short8 av1 = *(const short8*)(ga1 + k0);
    short8 bv0 = *(const short8*)(gb0 + k0);
    short8 bv1 = *(const short8*)(gb1 + k0);
    __syncthreads();                       // readers of prev tile done
    *(short8*)&As[(r0)      * 32 + kc] = av0;
    *(short8*)&As[(64 + r0) * 32 + kc] = av1;
    *(short8*)&Bs[(r0)      * 32 + kc] = bv0;
    *(short8*)&Bs[(64 + r0) * 32 + kc] = bv1;
    __syncthreads();                       // tile visible
    short8 af[4], bfr[4];
#pragma unroll
    for (int m = 0; m < 4; ++m)
      af[m] = *(const short8*)&As[(wm + m * 16 + l16) * 32 + l4 * 8];
#pragma unroll
    for (int n = 0; n < 4; ++n)
      bfr[n] = *(const short8*)&Bs[(wn + n * 16 + l16) * 32 + l4 * 8];
#pragma unroll
    for (int m = 0; m < 4; ++m)
#pragma unroll
      for (int n = 0; n < 4; ++n)
        acc[m][n] = mfma16(af[m], bfr[n], acc[m][n]);
  }

  // epilogue: C/D layout col=lane&15, row=(lane>>4)*4+reg
#pragma unroll
  for (int m = 0; m < 4; ++m) {
#pragma unroll
    for (int n = 0; n < 4; ++n) {
#pragma unroll
      for (int r = 0; r < 4; ++r) {
        size_t row = bm + wm + m * 16 + l4 * 4 + r;
        size_t col = bn + wn + n * 16 + l16;
        if constexpr (sizeof(OutT) == 2)
          C[row * N + col] = f2bf(acc[m][n][r]);
        else
          C[row * N + col] = acc[m][n][r];
      }
    }
  }
}

// ---------------- flash attention (round 3) --------------------------------
// grid (S/64, B*H); 4 waves/block, wave owns 16 q rows; KBLK=64 keys/iter.
// Swapped QK^T: s = mfma(K, Q) => lane l16 owns q=l16; softmax in-register.
// Q pre-scaled by 1/sqrt(128)*log2(e) during RoPE; exp2 domain throughout.
__global__ __launch_bounds__(256, 4) void flash_attn(const ushort* __restrict__ Q,
                                                     const ushort* __restrict__ K,
                                                     const ushort* __restrict__ Vt,
                                                     ushort* __restrict__ Oa) {
  __shared__ ushort Ks[64 * 128];       // [key][d], swizzled
  __shared__ ushort Vs[128 * 64];       // [d][key], swizzled
  __shared__ ushort Ps[4][16 * 64];     // per-wave P [q][key], swizzled
  const int tid = threadIdx.x;
  const int lane = tid & 63, wave = tid >> 6;
  const int l16 = lane & 15, l4 = lane >> 4;
  const int bh = blockIdx.y;
  const int b = bh >> 4, h = bh & 15, kv = h & 3;
  const int q0 = blockIdx.x * 64 + wave * 16;

  // Q fragments: lane holds Q[q0+l16][d-slice]; serves as B-op (and A-op) data
  short8 qf[4];
  const ushort* qrow = Q + ((size_t)(b * S_ + q0 + l16)) * D_ + h * DH_ + l4 * 8;
#pragma unroll
  for (int kk = 0; kk < 4; ++kk) qf[kk] = *(const short8*)(qrow + kk * 32);

  // cooperative staging: K rows are 256B (16 thr/row), V rows 128B (8 thr/row)
  const int krow = tid >> 4, kcol = (tid & 15) * 8;
  const int vrow = tid >> 3, vcol = (tid & 7) * 8;
  const ushort* kbase = K  + ((size_t)b * S_ + krow) * (HKV_ * DH_) + kv * DH_ + kcol;
  const ushort* vbase = Vt + ((size_t)(b * HKV_ + kv) * DH_ + vrow) * S_ + vcol;
  int kw[4], vw[4];
#pragma unroll
  for (int p = 0; p < 4; ++p) {
    int r = krow + p * 16;
    kw[p] = r * 128 + (kcol ^ ((r & 7) << 3));
    int d = vrow + p * 32;
    vw[p] = d * 64 + (vcol ^ ((d & 7) << 3));
  }

  float mreg = -1e30f, lsum = 0.f;      // per-lane stats for q = l16
  f32x4 o[8] = {};

  const int NT = S_ / 64;
  short8 kr[4], vr[4];
  auto loadt = [&](int t) {
#pragma unroll
    for (int p = 0; p < 4; ++p) {
      kr[p] = *(const short8*)(kbase + ((size_t)t * 64 + p * 16) * (HKV_ * DH_));
      vr[p] = *(const short8*)(vbase + (size_t)p * 32 * S_ + t * 64);
    }
  };

  loadt(0);
  for (int t = 0; t < NT; ++t) {
    __syncthreads();                      // all waves done reading prev tile
#pragma unroll
    for (int p = 0; p < 4; ++p) {
      *(short8*)&Ks[kw[p]] = kr[p];
      *(short8*)&Vs[vw[p]] = vr[p];
    }
    __syncthreads();                      // tile visible
    if (t + 1 < NT) loadt(t + 1);         // prefetch overlaps compute (T14)

    // QK^T swapped: s[c] = K-block(c) x Q -> D[key][q], q=l16,
    // lane's scores: key = c*16 + l4*4 + r
    f32x4 s[4] = {};
#pragma unroll
    for (int c = 0; c < 4; ++c) {
      const int key = c * 16 + l16;
      const int swz = (key & 7) << 3;
#pragma unroll
      for (int kk = 0; kk < 4; ++kk) {
        short8 kf = *(const short8*)&Ks[key * 128 + ((kk * 32 + l4 * 8) ^ swz)];
        s[c] = mfma16(kf, qf[kk], s[c]);
      }
    }

    // in-register softmax for q=l16 (scores already in exp2 domain)
    float tmax = -1e30f;
#pragma unroll
    for (int c = 0; c < 4; ++c) {
      float a = fmaxf(s[c][0], s[c][1]), bmx = fmaxf(s[c][2], s[c][3]);
      tmax = fmaxf(tmax, fmaxf(a, bmx));
    }
    tmax = fmaxf(tmax, __shfl_xor(tmax, 16));
    tmax = fmaxf(tmax, __shfl_xor(tmax, 32));

    if (!__all(tmax - mreg <= 8.0f)) {    // defer-max (T13): rare rescale
      float mn = fmaxf(mreg, tmax);
      float alpha = __builtin_amdgcn_exp2f(mreg - mn);
      mreg = mn;
      lsum *= alpha;
      float af[4];
#pragma unroll
      for (int r = 0; r < 4; ++r)
        af[r] = __shfl(alpha, (lane & 48) + l4 * 4 + r);
#pragma unroll
      for (int g = 0; g < 8; ++g)
#pragma unroll
        for (int r = 0; r < 4; ++r) o[g][r] *= af[r];
    }

    float rs = 0.f;
#pragma unroll
    for (int c = 0; c < 4; ++c) {
      float p0 = __builtin_amdgcn_exp2f(s[c][0] - mreg);
      float p1 = __builtin_amdgcn_exp2f(s[c][1] - mreg);
      float p2 = __builtin_amdgcn_exp2f(s[c][2] - mreg);
      float p3 = __builtin_amdgcn_exp2f(s[c][3] - mreg);
      rs += (p0 + p1) + (p2 + p3);
      ushort4 pk;
      pk.x = f2bf(p0); pk.y = f2bf(p1); pk.z = f2bf(p2); pk.w = f2bf(p3);
      // P[q=l16][key = c*16 + l4*4 .. +3], packed 8B store, swizzled row
      *(ushort4*)&Ps[wave][l16 * 64 + ((c * 16 + l4 * 4) ^ ((l16 & 7) << 3))] = pk;
    }
    rs += __shfl_xor(rs, 16);
    rs += __shfl_xor(rs, 32);
    lsum += rs;

    // PV: A = P[16q][64k] from Ps; B = V^T[k][d] from Vs
    const int pswzA = (l16 & 7) << 3;
#pragma unroll
    for (int ks = 0; ks < 2; ++ks) {
      short8 pa = *(const short8*)&Ps[wave][l16 * 64 + ((ks * 32 + l4 * 8) ^ pswzA)];
#pragma unroll
      for (int g = 0; g < 8; ++g) {
        const int d = g * 16 + l16;
        short8 vf = *(const short8*)&Vs[d * 64 + ((ks * 32 + l4 * 8) ^ ((d & 7) << 3))];
        o[g] = mfma16(pa, vf, o[g]);
      }
    }
  }

  // epilogue: O rows are q = l4*4+r; fetch 1/l from lane with l16 == q
  float inv = 1.0f / lsum;
  float invq[4];
#pragma unroll
  for (int r = 0; r < 4; ++r)
    invq[r] = __shfl(inv, (lane & 48) + l4 * 4 + r);
  ushort* op = Oa + (size_t)(b * S_ + q0) * D_ + h * DH_;
#pragma unroll
  for (int g = 0; g < 8; ++g)
#pragma unroll
    for (int r = 0; r < 4; ++r)
      op[(size_t)(l4 * 4 + r) * D_ + g * 16 + l16] = f2bf(o[g][r] * invq[r]);
}

// ---------------------------------------------------------------------------
extern "C" void kernel_launch(void* const* d_in, const int* in_sizes, int n_in,
                              void* d_out, int out_size, void* d_ws, size_t ws_size,
                              hipStream_t stream) {
  (void)in_sizes; (void)n_in; (void)out_size; (void)ws_size;
  const float* x  = (const float*)d_in[0];
  const float* Wq = (const float*)d_in[1];
  const float* Wk = (const float*)d_in[2];
  const float* Wv = (const float*)d_in[3];
  const float* Wo = (const float*)d_in[4];
  float* out = (float*)d_out;

  size_t off = 0;
  auto carve = [&](size_t bytes) -> void* {
    void* p = (char*)d_ws + off;
    off += (bytes + 255) & ~(size_t)255;
    return p;
  };
  ushort* xb   = (ushort*)carve((size_t)M_ * D_ * 2);
  ushort* Wqt  = (ushort*)carve((size_t)D_ * D_ * 2);
  ushort* Wkt  = (ushort*)carve((size_t)512 * D_ * 2);
  ushort* Wvt  = (ushort*)carve((size_t)512 * D_ * 2);
  ushort* Wot  = (ushort*)carve((size_t)D_ * D_ * 2);
  ushort* Qb   = (ushort*)carve((size_t)M_ * D_ * 2);
  ushort* Kb   = (ushort*)carve((size_t)M_ * 512 * 2);
  ushort* Vb   = (ushort*)carve((size_t)M_ * 512 * 2);
  ushort* Vt   = (ushort*)carve((size_t)M_ * 512 * 2);
  ushort* attn = (ushort*)carve((size_t)M_ * D_ * 2);
  float2* tab  = (float2*)carve((size_t)S_ * 64 * sizeof(float2));

  // 1. casts / transposes of inputs
  conv_f32_bf16<<<(M_ * D_ / 4 + 255) / 256, 256, 0, stream>>>(x, xb, M_ * D_ / 4);
  transpose_conv<<<dim3(64, 64), dim3(32, 8), 0, stream>>>(Wq, Wqt, 2048, 2048);
  transpose_conv<<<dim3(16, 64), dim3(32, 8), 0, stream>>>(Wk, Wkt, 2048, 512);
  transpose_conv<<<dim3(16, 64), dim3(32, 8), 0, stream>>>(Wv, Wvt, 2048, 512);
  transpose_conv<<<dim3(64, 64), dim3(32, 8), 0, stream>>>(Wo, Wot, 2048, 2048);
  rope_table_k<<<(S_ * 64) / 256, 256, 0, stream>>>(tab);

  // 2. projections
  gemm_bt<ushort><<<dim3(32, 16), 256, 0, stream>>>(xb, Wqt, Qb, M_, 2048, 2048);
  gemm_bt<ushort><<<dim3(32, 4),  256, 0, stream>>>(xb, Wkt, Kb, M_, 512, 2048);
  gemm_bt<ushort><<<dim3(32, 4),  256, 0, stream>>>(xb, Wvt, Vb, M_, 512, 2048);

  // 3. RoPE (in place; Q pre-scaled to exp2 domain), V transpose
  const float qscale = 0.08838834764831845f * 1.4426950408889634f;
  rope_apply_k<<<(M_ * 1024) / 256, 256, 0, stream>>>(Qb, tab, M_ * 1024, 10, qscale);
  rope_apply_k<<<(M_ * 256) / 256, 256, 0, stream>>>(Kb, tab, M_ * 256, 8, 1.0f);
  transpose_v<<<dim3(4, 64, 8), dim3(32, 8), 0, stream>>>(Vb, Vt);

  // 4. attention
  flash_attn<<<dim3(S_ / 64, B_ * H_), 256, 0, stream>>>(Qb, Kb, Vt, attn);

  // 5. output projection (f32 out)
  gemm_bt<float><<<dim3(32, 16), 256, 0, stream>>>(attn, Wot, out, M_, 2048, 2048);
}

// Round 4
// 273.385 us; speedup vs baseline: 2.5020x; 1.2661x over previous
//
#include <hip/hip_runtime.h>

// ---------------------------------------------------------------------------
// RoPE GQA attention block, MI355X bf16-MFMA implementation (round 4).
// B=2 S=2048 D=2048 H=16 HKV=4 DH=128.  head h uses kv head h%4 (torch tile).
// Round 4: GEMMs use global_load_lds width-16 (m97 structure); Q/K/V fused
// into one N=3072 GEMM (full-GPU grid); native bf16 casts (v_cvt_pk).
// ---------------------------------------------------------------------------

typedef __attribute__((ext_vector_type(8))) short  short8;
typedef __attribute__((ext_vector_type(8))) __bf16 bf16x8;
typedef __attribute__((ext_vector_type(4))) float  f32x4;

#define B_   2
#define S_   2048
#define D_   2048
#define H_   16
#define HKV_ 4
#define DH_  128
#define M_   4096  // B*S
#define NQKV 3072  // fused projection width: 2048 Q + 512 K + 512 V

static __device__ __forceinline__ ushort f2bf(float f) {
  __bf16 h = (__bf16)f;                      // native cvt (RNE)
  return __builtin_bit_cast(unsigned short, h);
}
static __device__ __forceinline__ float bf2f(ushort u) {
  union { unsigned u; float f; } v; v.u = ((unsigned)u) << 16;
  return v.f;
}
static __device__ __forceinline__ f32x4 mfma16(short8 a, short8 b, f32x4 c) {
  return __builtin_amdgcn_mfma_f32_16x16x32_bf16(
      __builtin_bit_cast(bf16x8, a), __builtin_bit_cast(bf16x8, b), c, 0, 0, 0);
}
// async global->LDS, 16B per lane; lds base must be wave-uniform.
static __device__ __forceinline__ void gload16(const ushort* g, ushort* l) {
  __builtin_amdgcn_global_load_lds(
      (const __attribute__((address_space(1))) unsigned int*)g,
      (__attribute__((address_space(3))) unsigned int*)l, 16, 0, 0);
}

// ---------------- elementwise f32 -> bf16 ----------------------------------
__global__ void conv_f32_bf16(const float* __restrict__ in,
                              ushort* __restrict__ out, int n4) {
  int i = blockIdx.x * blockDim.x + threadIdx.x;
  if (i >= n4) return;
  float4 v = ((const float4*)in)[i];
  ushort4 o;
  o.x = f2bf(v.x); o.y = f2bf(v.y); o.z = f2bf(v.z); o.w = f2bf(v.w);
  ((ushort4*)out)[i] = o;
}

// ---------------- transpose + convert: W[R][C] f32 -> Wt[C][R] bf16 --------
__global__ void transpose_conv(const float* __restrict__ in,
                               ushort* __restrict__ out, int R, int C) {
  __shared__ float tile[32][33];
  int c0 = blockIdx.x * 32, r0 = blockIdx.y * 32;
  int tx = threadIdx.x, ty = threadIdx.y;  // (32,8)
#pragma unroll
  for (int i = 0; i < 32; i += 8)
    tile[ty + i][tx] = in[(size_t)(r0 + ty + i) * C + c0 + tx];
  __syncthreads();
#pragma unroll
  for (int i = 0; i < 32; i += 8)
    out[(size_t)(c0 + ty + i) * R + r0 + tx] = f2bf(tile[tx][ty + i]);
}

// ---------------- bf16 transpose for V: QKV[.,2560+kv*128+d] -> [B,kv,128,S]
__global__ void transpose_v(const ushort* __restrict__ in,
                            ushort* __restrict__ out, int src_stride) {
  __shared__ ushort tile[32][33];
  int bkv = blockIdx.z;                       // b*4+kv
  const ushort* src = in + (size_t)(bkv >> 2) * S_ * src_stride + (bkv & 3) * DH_;
  ushort* dst = out + (size_t)bkv * DH_ * S_;
  int d0 = blockIdx.x * 32, s0 = blockIdx.y * 32;
  int tx = threadIdx.x, ty = threadIdx.y;
#pragma unroll
  for (int i = 0; i < 32; i += 8)
    tile[ty + i][tx] = src[(size_t)(s0 + ty + i) * src_stride + d0 + tx];
  __syncthreads();
#pragma unroll
  for (int i = 0; i < 32; i += 8)
    dst[(size_t)(d0 + ty + i) * S_ + s0 + tx] = tile[tx][ty + i];
}

// ---------------- RoPE cos/sin table [S][64] -------------------------------
__global__ void rope_table_k(float2* __restrict__ tab) {
  int i = blockIdx.x * blockDim.x + threadIdx.x;  // < S_*64
  int pos = i >> 6, f = i & 63;
  float freq = powf(10000.0f, -(float)f / 64.0f);
  float a = (float)pos * freq;
  tab[i] = make_float2(cosf(a), sinf(a));
}

// ---------------- RoPE in-place on bf16, strided rows ----------------------
__global__ void rope_apply_k(ushort* __restrict__ t,
                             const float2* __restrict__ tab,
                             int total, int ppr_shift, int row_stride,
                             float oscale) {
  int idx = blockIdx.x * blockDim.x + threadIdx.x;
  if (idx >= total) return;
  int row = idx >> ppr_shift;
  int p   = idx & ((1 << ppr_shift) - 1);
  int head = p >> 6, fi = p & 63;
  int pos = row & (S_ - 1);
  float2 cs = tab[(pos << 6) + fi];
  size_t off = (size_t)row * row_stride + head * DH_ + 2 * fi;
  ushort2 v = *(ushort2*)&t[off];
  float x0 = bf2f(v.x), x1 = bf2f(v.y);
  ushort2 o;
  o.x = f2bf((x0 * cs.x - x1 * cs.y) * oscale);
  o.y = f2bf((x0 * cs.y + x1 * cs.x) * oscale);
  *(ushort2*)&t[off] = o;
}

// ---------------- bf16 GEMM: C[M,N] = A[M,K] * Bt[N,K]^T -------------------
// m97 structure: 128x128 tile, BK=32, 4 waves (2x2), global_load_lds w16.
template <typename OutT>
__global__ __launch_bounds__(256) void gemm_bt(const ushort* __restrict__ A,
                                               const ushort* __restrict__ Bt,
                                               OutT* __restrict__ C,
                                               int M, int N, int K) {
  __shared__ ushort As[128 * 32];
  __shared__ ushort Bs[128 * 32];
  const int tid = threadIdx.x;
  const int lane = tid & 63, wave = tid >> 6;
  const int wm = (wave >> 1) * 64, wn = (wave & 1) * 64;
  const int bm = blockIdx.x * 128, bn = blockIdx.y * 128;
  const int l16 = lane & 15, l4 = lane >> 4;

  // staging: thread -> row tid>>2 (=wave*16+lane>>2), cols (tid&3)*8..+7
  const ushort* gA = A  + (size_t)(bm + (tid >> 2)) * K + (tid & 3) * 8;
  const ushort* gB = Bt + (size_t)(bn + (tid >> 2)) * K + (tid & 3) * 8;
  ushort* lA0 = &As[wave * 512];          // rows 0..63 (lane*16B linear)
  ushort* lA1 = &As[2048 + wave * 512];   // rows 64..127
  ushort* lB0 = &Bs[wave * 512];
  ushort* lB1 = &Bs[2048 + wave * 512];
  const size_t rstep = (size_t)64 * K;

  f32x4 acc[4][4] = {};

  for (int k0 = 0; k0 < K; k0 += 32) {
    __syncthreads();                       // readers of prev tile done
    gload16(gA + k0,         lA0);
    gload16(gA + k0 + rstep, lA1);
    gload16(gB + k0,         lB0);
    gload16(gB + k0 + rstep, lB1);
    __syncthreads();                       // vmcnt(0) drained -> tile visible
    short8 af[4], bfr[4];
#pragma unroll
    for (int m = 0; m < 4; ++m)
      af[m] = *(const short8*)&As[(wm + m * 16 + l16) * 32 + l4 * 8];
#pragma unroll
    for (int n = 0; n < 4; ++n)
      bfr[n] = *(const short8*)&Bs[(wn + n * 16 + l16) * 32 + l4 * 8];
#pragma unroll
    for (int m = 0; m < 4; ++m)
#pragma unroll
      for (int n = 0; n < 4; ++n)
        acc[m][n] = mfma16(af[m], bfr[n], acc[m][n]);
  }

  // epilogue: C/D layout col=lane&15, row=(lane>>4)*4+reg
#pragma unroll
  for (int m = 0; m < 4; ++m) {
#pragma unroll
    for (int n = 0; n < 4; ++n) {
#pragma unroll
      for (int r = 0; r < 4; ++r) {
        size_t row = bm + wm + m * 16 + l4 * 4 + r;
        size_t col = bn + wn + n * 16 + l16;
        if constexpr (sizeof(OutT) == 2)
          C[row * N + col] = f2bf(acc[m][n][r]);
        else
          C[row * N + col] = acc[m][n][r];
      }
    }
  }
}

// ---------------- flash attention ------------------------------------------
// grid (S/64, B*H); 4 waves/block, wave owns 16 q rows; KBLK=64 keys/iter.
// Swapped QK^T: s = mfma(K, Q) => lane l16 owns q=l16; softmax in-register.
// Q pre-scaled by 1/sqrt(128)*log2(e) during RoPE; exp2 domain throughout.
// Q/K live in the fused QKV buffer (row stride NQKV).
__global__ __launch_bounds__(256, 4) void flash_attn(const ushort* __restrict__ Qp,
                                                     const ushort* __restrict__ Kp,
                                                     const ushort* __restrict__ Vt,
                                                     ushort* __restrict__ Oa) {
  __shared__ ushort Ks[64 * 128];       // [key][d], swizzled
  __shared__ ushort Vs[128 * 64];       // [d][key], swizzled
  __shared__ ushort Ps[4][16 * 64];     // per-wave P [q][key], swizzled
  const int tid = threadIdx.x;
  const int lane = tid & 63, wave = tid >> 6;
  const int l16 = lane & 15, l4 = lane >> 4;
  const int bh = blockIdx.y;
  const int b = bh >> 4, h = bh & 15, kv = h & 3;
  const int q0 = blockIdx.x * 64 + wave * 16;

  // Q fragments: lane holds Q[q0+l16][d-slice]
  short8 qf[4];
  const ushort* qrow = Qp + ((size_t)(b * S_ + q0 + l16)) * NQKV + h * DH_ + l4 * 8;
#pragma unroll
  for (int kk = 0; kk < 4; ++kk) qf[kk] = *(const short8*)(qrow + kk * 32);

  // cooperative staging: K rows 256B (16 thr/row), V rows 128B (8 thr/row)
  const int krow = tid >> 4, kcol = (tid & 15) * 8;
  const int vrow = tid >> 3, vcol = (tid & 7) * 8;
  const ushort* kbase = Kp + ((size_t)b * S_ + krow) * NQKV + kv * DH_ + kcol;
  const ushort* vbase = Vt + ((size_t)(b * HKV_ + kv) * DH_ + vrow) * S_ + vcol;
  int kw[4], vw[4];
#pragma unroll
  for (int p = 0; p < 4; ++p) {
    int r = krow + p * 16;
    kw[p] = r * 128 + (kcol ^ ((r & 7) << 3));
    int d = vrow + p * 32;
    vw[p] = d * 64 + (vcol ^ ((d & 7) << 3));
  }

  float mreg = -1e30f, lsum = 0.f;      // per-lane stats for q = l16
  f32x4 o[8] = {};

  const int NT = S_ / 64;
  short8 kr[4], vr[4];
  auto loadt = [&](int t) {
#pragma unroll
    for (int p = 0; p < 4; ++p) {
      kr[p] = *(const short8*)(kbase + ((size_t)t * 64 + p * 16) * NQKV);
      vr[p] = *(const short8*)(vbase + (size_t)p * 32 * S_ + t * 64);
    }
  };

  loadt(0);
  for (int t = 0; t < NT; ++t) {
    __syncthreads();                      // all waves done reading prev tile
#pragma unroll
    for (int p = 0; p < 4; ++p) {
      *(short8*)&Ks[kw[p]] = kr[p];
      *(short8*)&Vs[vw[p]] = vr[p];
    }
    __syncthreads();                      // tile visible
    if (t + 1 < NT) loadt(t + 1);         // prefetch overlaps compute (T14)

    // QK^T swapped: lane's scores: key = c*16 + l4*4 + r, q = l16
    f32x4 s[4] = {};
#pragma unroll
    for (int c = 0; c < 4; ++c) {
      const int key = c * 16 + l16;
      const int swz = (key & 7) << 3;
#pragma unroll
      for (int kk = 0; kk < 4; ++kk) {
        short8 kf = *(const short8*)&Ks[key * 128 + ((kk * 32 + l4 * 8) ^ swz)];
        s[c] = mfma16(kf, qf[kk], s[c]);
      }
    }

    // in-register softmax for q=l16 (scores already in exp2 domain)
    float tmax = -1e30f;
#pragma unroll
    for (int c = 0; c < 4; ++c) {
      float a = fmaxf(s[c][0], s[c][1]), bmx = fmaxf(s[c][2], s[c][3]);
      tmax = fmaxf(tmax, fmaxf(a, bmx));
    }
    tmax = fmaxf(tmax, __shfl_xor(tmax, 16));
    tmax = fmaxf(tmax, __shfl_xor(tmax, 32));

    if (!__all(tmax - mreg <= 8.0f)) {    // defer-max (T13): rare rescale
      float mn = fmaxf(mreg, tmax);
      float alpha = __builtin_amdgcn_exp2f(mreg - mn);
      mreg = mn;
      lsum *= alpha;
      float af[4];
#pragma unroll
      for (int r = 0; r < 4; ++r)
        af[r] = __shfl(alpha, (lane & 48) + l4 * 4 + r);
#pragma unroll
      for (int g = 0; g < 8; ++g)
#pragma unroll
        for (int r = 0; r < 4; ++r) o[g][r] *= af[r];
    }

    float rs = 0.f;
#pragma unroll
    for (int c = 0; c < 4; ++c) {
      float p0 = __builtin_amdgcn_exp2f(s[c][0] - mreg);
      float p1 = __builtin_amdgcn_exp2f(s[c][1] - mreg);
      float p2 = __builtin_amdgcn_exp2f(s[c][2] - mreg);
      float p3 = __builtin_amdgcn_exp2f(s[c][3] - mreg);
      rs += (p0 + p1) + (p2 + p3);
      ushort4 pk;
      pk.x = f2bf(p0); pk.y = f2bf(p1); pk.z = f2bf(p2); pk.w = f2bf(p3);
      *(ushort4*)&Ps[wave][l16 * 64 + ((c * 16 + l4 * 4) ^ ((l16 & 7) << 3))] = pk;
    }
    rs += __shfl_xor(rs, 16);
    rs += __shfl_xor(rs, 32);
    lsum += rs;

    // PV: A = P[16q][64k] from Ps; B = V^T[k][d] from Vs
    const int pswzA = (l16 & 7) << 3;
#pragma unroll
    for (int ks = 0; ks < 2; ++ks) {
      short8 pa = *(const short8*)&Ps[wave][l16 * 64 + ((ks * 32 + l4 * 8) ^ pswzA)];
#pragma unroll
      for (int g = 0; g < 8; ++g) {
        const int d = g * 16 + l16;
        short8 vf = *(const short8*)&Vs[d * 64 + ((ks * 32 + l4 * 8) ^ ((d & 7) << 3))];
        o[g] = mfma16(pa, vf, o[g]);
      }
    }
  }

  // epilogue: O rows are q = l4*4+r; fetch 1/l from lane with l16 == q
  float inv = 1.0f / lsum;
  float invq[4];
#pragma unroll
  for (int r = 0; r < 4; ++r)
    invq[r] = __shfl(inv, (lane & 48) + l4 * 4 + r);
  ushort* op = Oa + (size_t)(b * S_ + q0) * D_ + h * DH_;
#pragma unroll
  for (int g = 0; g < 8; ++g)
#pragma unroll
    for (int r = 0; r < 4; ++r)
      op[(size_t)(l4 * 4 + r) * D_ + g * 16 + l16] = f2bf(o[g][r] * invq[r]);
}

// ---------------------------------------------------------------------------
extern "C" void kernel_launch(void* const* d_in, const int* in_sizes, int n_in,
                              void* d_out, int out_size, void* d_ws, size_t ws_size,
                              hipStream_t stream) {
  (void)in_sizes; (void)n_in; (void)out_size; (void)ws_size;
  const float* x  = (const float*)d_in[0];
  const float* Wq = (const float*)d_in[1];
  const float* Wk = (const float*)d_in[2];
  const float* Wv = (const float*)d_in[3];
  const float* Wo = (const float*)d_in[4];
  float* out = (float*)d_out;

  size_t off = 0;
  auto carve = [&](size_t bytes) -> void* {
    void* p = (char*)d_ws + off;
    off += (bytes + 255) & ~(size_t)255;
    return p;
  };
  ushort* xb    = (ushort*)carve((size_t)M_ * D_ * 2);
  ushort* Wqkvt = (ushort*)carve((size_t)NQKV * D_ * 2);   // [3072][2048]
  ushort* Wot   = (ushort*)carve((size_t)D_ * D_ * 2);
  ushort* QKV   = (ushort*)carve((size_t)M_ * NQKV * 2);   // [4096][3072]
  ushort* Vt    = (ushort*)carve((size_t)M_ * 512 * 2);
  ushort* attn  = (ushort*)carve((size_t)M_ * D_ * 2);
  float2* tab   = (float2*)carve((size_t)S_ * 64 * sizeof(float2));

  // 1. casts / transposes of inputs (K,V weight rows appended after Q's)
  conv_f32_bf16<<<(M_ * D_ / 4 + 255) / 256, 256, 0, stream>>>(x, xb, M_ * D_ / 4);
  transpose_conv<<<dim3(64, 64), dim3(32, 8), 0, stream>>>(Wq, Wqkvt, 2048, 2048);
  transpose_conv<<<dim3(16, 64), dim3(32, 8), 0, stream>>>(Wk, Wqkvt + (size_t)2048 * 2048, 2048, 512);
  transpose_conv<<<dim3(16, 64), dim3(32, 8), 0, stream>>>(Wv, Wqkvt + (size_t)2560 * 2048, 2048, 512);
  transpose_conv<<<dim3(64, 64), dim3(32, 8), 0, stream>>>(Wo, Wot, 2048, 2048);
  rope_table_k<<<(S_ * 64) / 256, 256, 0, stream>>>(tab);

  // 2. fused QKV projection: [4096,2048] x [3072,2048]^T -> [4096,3072]
  gemm_bt<ushort><<<dim3(32, 24), 256, 0, stream>>>(xb, Wqkvt, QKV, M_, NQKV, 2048);

  // 3. RoPE in place (Q pre-scaled to exp2 domain), V transpose
  const float qscale = 0.08838834764831845f * 1.4426950408889634f;
  rope_apply_k<<<(M_ * 1024) / 256, 256, 0, stream>>>(QKV, tab, M_ * 1024, 10, NQKV, qscale);
  rope_apply_k<<<(M_ * 256) / 256, 256, 0, stream>>>(QKV + 2048, tab, M_ * 256, 8, NQKV, 1.0f);
  transpose_v<<<dim3(4, 64, 8), dim3(32, 8), 0, stream>>>(QKV + 2560, Vt, NQKV);

  // 4. attention
  flash_attn<<<dim3(S_ / 64, B_ * H_), 256, 0, stream>>>(QKV, QKV + 2048, Vt, attn);

  // 5. output projection (f32 out)
  gemm_bt<float><<<dim3(32, 16), 256, 0, stream>>>(attn, Wot, out, M_, 2048, 2048);
}

// Round 5
// 242.005 us; speedup vs baseline: 2.8264x; 1.1297x over previous
//
#include <hip/hip_runtime.h>

// ---------------------------------------------------------------------------
// RoPE GQA attention block, MI355X bf16-MFMA implementation (round 5).
// B=2 S=2048 D=2048 H=16 HKV=4 DH=128.  head h uses kv head h%4 (torch tile).
// Round 5: flash_attn rebuilt — 32 q/wave (2 q-groups share K/V fragments),
// in-register P via interleaved QK^T key mapping (zero P LDS traffic),
// K/V staged with global_load_lds + pre-swizzled source columns, setprio.
// ---------------------------------------------------------------------------

typedef __attribute__((ext_vector_type(8))) short  short8;
typedef __attribute__((ext_vector_type(8))) __bf16 bf16x8;
typedef __attribute__((ext_vector_type(4))) float  f32x4;

#define B_   2
#define S_   2048
#define D_   2048
#define H_   16
#define HKV_ 4
#define DH_  128
#define M_   4096  // B*S
#define NQKV 3072  // fused projection width: 2048 Q + 512 K + 512 V

static __device__ __forceinline__ ushort f2bf(float f) {
  __bf16 h = (__bf16)f;                      // native cvt (RNE)
  return __builtin_bit_cast(unsigned short, h);
}
static __device__ __forceinline__ float bf2f(ushort u) {
  union { unsigned u; float f; } v; v.u = ((unsigned)u) << 16;
  return v.f;
}
static __device__ __forceinline__ f32x4 mfma16(short8 a, short8 b, f32x4 c) {
  return __builtin_amdgcn_mfma_f32_16x16x32_bf16(
      __builtin_bit_cast(bf16x8, a), __builtin_bit_cast(bf16x8, b), c, 0, 0, 0);
}
// async global->LDS, 16B per lane; lds base must be wave-uniform.
static __device__ __forceinline__ void gload16(const ushort* g, ushort* l) {
  __builtin_amdgcn_global_load_lds(
      (const __attribute__((address_space(1))) unsigned int*)g,
      (__attribute__((address_space(3))) unsigned int*)l, 16, 0, 0);
}

// ---------------- elementwise f32 -> bf16 ----------------------------------
__global__ void conv_f32_bf16(const float* __restrict__ in,
                              ushort* __restrict__ out, int n4) {
  int i = blockIdx.x * blockDim.x + threadIdx.x;
  if (i >= n4) return;
  float4 v = ((const float4*)in)[i];
  ushort4 o;
  o.x = f2bf(v.x); o.y = f2bf(v.y); o.z = f2bf(v.z); o.w = f2bf(v.w);
  ((ushort4*)out)[i] = o;
}

// ---------------- transpose + convert: W[R][C] f32 -> Wt[C][R] bf16 --------
__global__ void transpose_conv(const float* __restrict__ in,
                               ushort* __restrict__ out, int R, int C) {
  __shared__ float tile[32][33];
  int c0 = blockIdx.x * 32, r0 = blockIdx.y * 32;
  int tx = threadIdx.x, ty = threadIdx.y;  // (32,8)
#pragma unroll
  for (int i = 0; i < 32; i += 8)
    tile[ty + i][tx] = in[(size_t)(r0 + ty + i) * C + c0 + tx];
  __syncthreads();
#pragma unroll
  for (int i = 0; i < 32; i += 8)
    out[(size_t)(c0 + ty + i) * R + r0 + tx] = f2bf(tile[tx][ty + i]);
}

// ---------------- bf16 transpose for V: QKV[.,2560+kv*128+d] -> [B,kv,128,S]
__global__ void transpose_v(const ushort* __restrict__ in,
                            ushort* __restrict__ out, int src_stride) {
  __shared__ ushort tile[32][33];
  int bkv = blockIdx.z;                       // b*4+kv
  const ushort* src = in + (size_t)(bkv >> 2) * S_ * src_stride + (bkv & 3) * DH_;
  ushort* dst = out + (size_t)bkv * DH_ * S_;
  int d0 = blockIdx.x * 32, s0 = blockIdx.y * 32;
  int tx = threadIdx.x, ty = threadIdx.y;
#pragma unroll
  for (int i = 0; i < 32; i += 8)
    tile[ty + i][tx] = src[(size_t)(s0 + ty + i) * src_stride + d0 + tx];
  __syncthreads();
#pragma unroll
  for (int i = 0; i < 32; i += 8)
    dst[(size_t)(d0 + ty + i) * S_ + s0 + tx] = tile[tx][ty + i];
}

// ---------------- RoPE cos/sin table [S][64] -------------------------------
__global__ void rope_table_k(float2* __restrict__ tab) {
  int i = blockIdx.x * blockDim.x + threadIdx.x;  // < S_*64
  int pos = i >> 6, f = i & 63;
  float freq = powf(10000.0f, -(float)f / 64.0f);
  float a = (float)pos * freq;
  tab[i] = make_float2(cosf(a), sinf(a));
}

// ---------------- RoPE in-place on bf16, strided rows ----------------------
__global__ void rope_apply_k(ushort* __restrict__ t,
                             const float2* __restrict__ tab,
                             int total, int ppr_shift, int row_stride,
                             float oscale) {
  int idx = blockIdx.x * blockDim.x + threadIdx.x;
  if (idx >= total) return;
  int row = idx >> ppr_shift;
  int p   = idx & ((1 << ppr_shift) - 1);
  int head = p >> 6, fi = p & 63;
  int pos = row & (S_ - 1);
  float2 cs = tab[(pos << 6) + fi];
  size_t off = (size_t)row * row_stride + head * DH_ + 2 * fi;
  ushort2 v = *(ushort2*)&t[off];
  float x0 = bf2f(v.x), x1 = bf2f(v.y);
  ushort2 o;
  o.x = f2bf((x0 * cs.x - x1 * cs.y) * oscale);
  o.y = f2bf((x0 * cs.y + x1 * cs.x) * oscale);
  *(ushort2*)&t[off] = o;
}

// ---------------- bf16 GEMM: C[M,N] = A[M,K] * Bt[N,K]^T -------------------
// m97 structure: 128x128 tile, BK=32, 4 waves (2x2), global_load_lds w16.
template <typename OutT>
__global__ __launch_bounds__(256) void gemm_bt(const ushort* __restrict__ A,
                                               const ushort* __restrict__ Bt,
                                               OutT* __restrict__ C,
                                               int M, int N, int K) {
  __shared__ ushort As[128 * 32];
  __shared__ ushort Bs[128 * 32];
  const int tid = threadIdx.x;
  const int lane = tid & 63, wave = tid >> 6;
  const int wm = (wave >> 1) * 64, wn = (wave & 1) * 64;
  const int bm = blockIdx.x * 128, bn = blockIdx.y * 128;
  const int l16 = lane & 15, l4 = lane >> 4;

  // staging: thread -> row tid>>2 (=wave*16+lane>>2), cols (tid&3)*8..+7
  const ushort* gA = A  + (size_t)(bm + (tid >> 2)) * K + (tid & 3) * 8;
  const ushort* gB = Bt + (size_t)(bn + (tid >> 2)) * K + (tid & 3) * 8;
  ushort* lA0 = &As[wave * 512];          // rows 0..63 (lane*16B linear)
  ushort* lA1 = &As[2048 + wave * 512];   // rows 64..127
  ushort* lB0 = &Bs[wave * 512];
  ushort* lB1 = &Bs[2048 + wave * 512];
  const size_t rstep = (size_t)64 * K;

  f32x4 acc[4][4] = {};

  for (int k0 = 0; k0 < K; k0 += 32) {
    __syncthreads();                       // readers of prev tile done
    gload16(gA + k0,         lA0);
    gload16(gA + k0 + rstep, lA1);
    gload16(gB + k0,         lB0);
    gload16(gB + k0 + rstep, lB1);
    __syncthreads();                       // vmcnt(0) drained -> tile visible
    short8 af[4], bfr[4];
#pragma unroll
    for (int m = 0; m < 4; ++m)
      af[m] = *(const short8*)&As[(wm + m * 16 + l16) * 32 + l4 * 8];
#pragma unroll
    for (int n = 0; n < 4; ++n)
      bfr[n] = *(const short8*)&Bs[(wn + n * 16 + l16) * 32 + l4 * 8];
#pragma unroll
    for (int m = 0; m < 4; ++m)
#pragma unroll
      for (int n = 0; n < 4; ++n)
        acc[m][n] = mfma16(af[m], bfr[n], acc[m][n]);
  }

  // epilogue: C/D layout col=lane&15, row=(lane>>4)*4+reg
#pragma unroll
  for (int m = 0; m < 4; ++m) {
#pragma unroll
    for (int n = 0; n < 4; ++n) {
#pragma unroll
      for (int r = 0; r < 4; ++r) {
        size_t row = bm + wm + m * 16 + l4 * 4 + r;
        size_t col = bn + wn + n * 16 + l16;
        if constexpr (sizeof(OutT) == 2)
          C[row * N + col] = f2bf(acc[m][n][r]);
        else
          C[row * N + col] = acc[m][n][r];
      }
    }
  }
}

// ---------------- flash attention (round 5) --------------------------------
// grid (S/128, B*H); 4 waves/block, wave owns 32 q rows (2 q-groups of 16);
// KBLK=64. Swapped QK^T with interleaved key mapping so the P fragments for
// PV are produced directly in registers (no P LDS round-trip):
//   s[qg][c][r] (lane l16,l4) = S[q=qg*16+l16][key = 32*(c>>1)+8*l4+4*(c&1)+r]
//   => pa[qg][ks][j] = P[q][ks*32 + l4*8 + j] = cvt(s[qg][2ks+(j>>2)][j&3]).
// K/V staged via global_load_lds w16 with source-pre-swizzled columns.
__global__ __launch_bounds__(256, 2) void flash_attn(const ushort* __restrict__ Qp,
                                                     const ushort* __restrict__ Kp,
                                                     const ushort* __restrict__ Vt,
                                                     ushort* __restrict__ Oa) {
  __shared__ ushort Ks[64 * 128];       // [key][d], swizzle (r&3)|((r>>3)&1)<<2
  __shared__ ushort Vs[128 * 64];       // [d][key], swizzle d&7
  const int tid = threadIdx.x;
  const int lane = tid & 63, wave = tid >> 6;
  const int l16 = lane & 15, l4 = lane >> 4;
  const int bh = blockIdx.y;
  const int b = bh >> 4, h = bh & 15, kv = h & 3;
  const int q0 = blockIdx.x * 128 + wave * 32;

  // Q fragments: 2 q-groups, lane holds Q[q0+qg*16+l16][d-slice]
  short8 qf[2][4];
#pragma unroll
  for (int qg = 0; qg < 2; ++qg) {
    const ushort* qrow =
        Qp + ((size_t)(b * S_ + q0 + qg * 16 + l16)) * NQKV + h * DH_ + l4 * 8;
#pragma unroll
    for (int kk = 0; kk < 4; ++kk) qf[qg][kk] = *(const short8*)(qrow + kk * 32);
  }

  const ushort* kbase = Kp + (size_t)(b * S_) * NQKV + kv * DH_;
  const ushort* vbase = Vt + (size_t)(b * HKV_ + kv) * DH_ * S_;

  float mreg[2] = {-1e30f, -1e30f}, lsum[2] = {0.f, 0.f};
  f32x4 o[2][8] = {};

  // read-side swizzles (constant per lane)
  const int kswz = (l16 & 3) | (((l16 >> 2) & 1) << 2);  // = swzK(krow) below
  const int vswz = l16 & 7;

  const int NT = S_ / 64;
  for (int t = 0; t < NT; ++t) {
    __syncthreads();                      // all waves done reading prev tile
    // ---- stage K[64][128] and V^T[128][64] via DMA, source pre-swizzled ----
#pragma unroll
    for (int i = 0; i < 4; ++i) {
      int r = wave * 16 + i * 4 + (lane >> 4);            // K tile row
      int swz = (r & 3) | (((r >> 3) & 1) << 2);
      gload16(kbase + (size_t)(t * 64 + r) * NQKV + (((lane & 15) ^ swz) * 8),
              &Ks[(wave * 16 + i * 4) * 128]);
      int d = wave * 32 + i * 8 + (lane >> 3);            // V tile row (d)
      gload16(vbase + (size_t)d * S_ + t * 64 + (((lane & 7) ^ (d & 7)) * 8),
              &Vs[(wave * 32 + i * 8) * 64]);
    }
    __syncthreads();                      // vmcnt(0) drained -> tiles visible

    // ---- QK^T (swapped, interleaved keys), K-fragments shared by 2 qg ----
    f32x4 s[2][4] = {};
    __builtin_amdgcn_s_setprio(1);
#pragma unroll
    for (int c = 0; c < 4; ++c) {
      const int krow = 32 * (c >> 1) + 8 * (l16 >> 2) + 4 * (c & 1) + (l16 & 3);
#pragma unroll
      for (int kk = 0; kk < 4; ++kk) {
        short8 kf = *(const short8*)&Ks[krow * 128 + (((kk * 4 + l4) ^ kswz) * 8)];
        s[0][c] = mfma16(kf, qf[0][kk], s[0][c]);
        s[1][c] = mfma16(kf, qf[1][kk], s[1][c]);
      }
    }
    __builtin_amdgcn_s_setprio(0);

    // ---- online softmax, per lane q = qg*16 + l16 (exp2 domain) ----
    float tmax[2];
#pragma unroll
    for (int qg = 0; qg < 2; ++qg) {
      float a = fmaxf(fmaxf(s[qg][0][0], s[qg][0][1]), fmaxf(s[qg][0][2], s[qg][0][3]));
#pragma unroll
      for (int c = 1; c < 4; ++c) {
        a = fmaxf(a, fmaxf(fmaxf(s[qg][c][0], s[qg][c][1]),
                           fmaxf(s[qg][c][2], s[qg][c][3])));
      }
      a = fmaxf(a, __shfl_xor(a, 16));
      tmax[qg] = fmaxf(a, __shfl_xor(a, 32));
    }

    bool ok = (tmax[0] - mreg[0] <= 8.0f) && (tmax[1] - mreg[1] <= 8.0f);
    if (!__all(ok)) {                     // defer-max (T13): rare rescale
#pragma unroll
      for (int qg = 0; qg < 2; ++qg) {
        float mn = fmaxf(mreg[qg], tmax[qg]);
        float alpha = __builtin_amdgcn_exp2f(mreg[qg] - mn);
        mreg[qg] = mn;
        lsum[qg] *= alpha;
        float af[4];
#pragma unroll
        for (int r = 0; r < 4; ++r)
          af[r] = __shfl(alpha, (lane & 48) + l4 * 4 + r);
#pragma unroll
        for (int g = 0; g < 8; ++g)
#pragma unroll
          for (int r = 0; r < 4; ++r) o[qg][g][r] *= af[r];
      }
    }

    // ---- P in registers: pa[qg][ks][j] = P[q][ks*32 + l4*8 + j] ----
    short8 pa[2][2];
    float rs[2] = {0.f, 0.f};
#pragma unroll
    for (int qg = 0; qg < 2; ++qg) {
#pragma unroll
      for (int ks = 0; ks < 2; ++ks) {
        short8 pk;
#pragma unroll
        for (int j = 0; j < 8; ++j) {
          float p = __builtin_amdgcn_exp2f(s[qg][2 * ks + (j >> 2)][j & 3] - mreg[qg]);
          rs[qg] += p;
          pk[j] = (short)f2bf(p);
        }
        pa[qg][ks] = pk;
      }
      float r2 = rs[qg] + __shfl_xor(rs[qg], 16);
      lsum[qg] += r2 + __shfl_xor(r2, 32);
    }

    // ---- PV: V-fragments shared by both q-groups ----
    __builtin_amdgcn_s_setprio(1);
#pragma unroll
    for (int ks = 0; ks < 2; ++ks) {
#pragma unroll
      for (int g = 0; g < 8; ++g) {
        const int d = g * 16 + l16;
        short8 vf = *(const short8*)&Vs[d * 64 + (((ks * 4 + l4) ^ vswz) * 8)];
        o[0][g] = mfma16(pa[0][ks], vf, o[0][g]);
        o[1][g] = mfma16(pa[1][ks], vf, o[1][g]);
      }
    }
    __builtin_amdgcn_s_setprio(0);
  }

  // epilogue: O rows are q = qg*16 + l4*4 + r; fetch 1/l from lane l16 == qrow
#pragma unroll
  for (int qg = 0; qg < 2; ++qg) {
    float inv = 1.0f / lsum[qg];
    float invq[4];
#pragma unroll
    for (int r = 0; r < 4; ++r)
      invq[r] = __shfl(inv, (lane & 48) + l4 * 4 + r);
    ushort* op = Oa + (size_t)(b * S_ + q0 + qg * 16) * D_ + h * DH_;
#pragma unroll
    for (int g = 0; g < 8; ++g)
#pragma unroll
      for (int r = 0; r < 4; ++r)
        op[(size_t)(l4 * 4 + r) * D_ + g * 16 + l16] = f2bf(o[qg][g][r] * invq[r]);
  }
}

// ---------------------------------------------------------------------------
extern "C" void kernel_launch(void* const* d_in, const int* in_sizes, int n_in,
                              void* d_out, int out_size, void* d_ws, size_t ws_size,
                              hipStream_t stream) {
  (void)in_sizes; (void)n_in; (void)out_size; (void)ws_size;
  const float* x  = (const float*)d_in[0];
  const float* Wq = (const float*)d_in[1];
  const float* Wk = (const float*)d_in[2];
  const float* Wv = (const float*)d_in[3];
  const float* Wo = (const float*)d_in[4];
  float* out = (float*)d_out;

  size_t off = 0;
  auto carve = [&](size_t bytes) -> void* {
    void* p = (char*)d_ws + off;
    off += (bytes + 255) & ~(size_t)255;
    return p;
  };
  ushort* xb    = (ushort*)carve((size_t)M_ * D_ * 2);
  ushort* Wqkvt = (ushort*)carve((size_t)NQKV * D_ * 2);   // [3072][2048]
  ushort* Wot   = (ushort*)carve((size_t)D_ * D_ * 2);
  ushort* QKV   = (ushort*)carve((size_t)M_ * NQKV * 2);   // [4096][3072]
  ushort* Vt    = (ushort*)carve((size_t)M_ * 512 * 2);
  ushort* attn  = (ushort*)carve((size_t)M_ * D_ * 2);
  float2* tab   = (float2*)carve((size_t)S_ * 64 * sizeof(float2));

  // 1. casts / transposes of inputs (K,V weight rows appended after Q's)
  conv_f32_bf16<<<(M_ * D_ / 4 + 255) / 256, 256, 0, stream>>>(x, xb, M_ * D_ / 4);
  transpose_conv<<<dim3(64, 64), dim3(32, 8), 0, stream>>>(Wq, Wqkvt, 2048, 2048);
  transpose_conv<<<dim3(16, 64), dim3(32, 8), 0, stream>>>(Wk, Wqkvt + (size_t)2048 * 2048, 2048, 512);
  transpose_conv<<<dim3(16, 64), dim3(32, 8), 0, stream>>>(Wv, Wqkvt + (size_t)2560 * 2048, 2048, 512);
  transpose_conv<<<dim3(64, 64), dim3(32, 8), 0, stream>>>(Wo, Wot, 2048, 2048);
  rope_table_k<<<(S_ * 64) / 256, 256, 0, stream>>>(tab);

  // 2. fused QKV projection: [4096,2048] x [3072,2048]^T -> [4096,3072]
  gemm_bt<ushort><<<dim3(32, 24), 256, 0, stream>>>(xb, Wqkvt, QKV, M_, NQKV, 2048);

  // 3. RoPE in place (Q pre-scaled to exp2 domain), V transpose
  const float qscale = 0.08838834764831845f * 1.4426950408889634f;
  rope_apply_k<<<(M_ * 1024) / 256, 256, 0, stream>>>(QKV, tab, M_ * 1024, 10, NQKV, qscale);
  rope_apply_k<<<(M_ * 256) / 256, 256, 0, stream>>>(QKV + 2048, tab, M_ * 256, 8, NQKV, 1.0f);
  transpose_v<<<dim3(4, 64, 8), dim3(32, 8), 0, stream>>>(QKV + 2560, Vt, NQKV);

  // 4. attention
  flash_attn<<<dim3(S_ / 128, B_ * H_), 256, 0, stream>>>(QKV, QKV + 2048, Vt, attn);

  // 5. output projection (f32 out)
  gemm_bt<float><<<dim3(32, 16), 256, 0, stream>>>(attn, Wot, out, M_, 2048, 2048);
}